// Round 9
// baseline (195.309 us; speedup 1.0000x reference)
//
#include <hip/hip_runtime.h>
#include <cstdint>
#include <cstddef>

#define HID 128
#define SEQL 28
#define INP 28
#define NL 10
#define NC 10
#define BATCH 4096
#define BB 16             // batch rows per block (1 block/CU; r7 settled occupancy)
#define STRD 136          // padded row stride in halfs (272 B, b128-aligned)
#define BUFH (16 * STRD)  // halfs per 16x128 activation buffer (4352 B)

// LDS map (dynamic): O(s,p) = slot s*2+p (s=0..2), SEQ(t) = slot 6+t (t=0..27)
// -> 34 slots x 4352 B = 147968 B; then 16 int flags. s3 reads/writes SEQ
// directly (its H = own SEQ(t-1)); s0 reads SEQ (g1/g2) or global x (g0).
#define NSLOT 34
#define FLAGS_HOFF (NSLOT * BUFH)            // offset in halfs
#define LDS_BYTES (NSLOT * BUFH * 2 + 64)
#define FBIG 1000

typedef _Float16 half8 __attribute__((ext_vector_type(8)));
typedef _Float16 half4 __attribute__((ext_vector_type(4)));
typedef float    f32x4 __attribute__((ext_vector_type(4)));

// ---------------- ws layout (bytes) ----------------
// Wcat : [NL][HID][256] f16 : 655360 @ 0   row n: [Wih(128, l0 zero-padded) | Whh(128)]
// bias : [NL][HID] f32      : 5120   @ 655360   (b_ih + b_hh)
#define WS_WCAT_OFF 0
#define WS_BIAS_OFF 655360

__global__ void convert_weights(const float* __restrict__ Wih0,
                                const float* __restrict__ Wih,
                                const float* __restrict__ Whh,
                                const float* __restrict__ bih,
                                const float* __restrict__ bhh,
                                _Float16* __restrict__ Wcat,
                                float* __restrict__ bias) {
  int tg = blockIdx.x * blockDim.x + threadIdx.x;
  if (tg >= NL * HID * 16) return;
  int r = tg >> 4, seg = tg & 15;
  int l = r / HID, n = r % HID;
  int k0 = seg * 16;
  _Float16* dst = Wcat + (size_t)r * 256 + k0;
  if (l == 0) {
#pragma unroll
    for (int i = 0; i < 16; ++i) {
      int k = k0 + i;
      float v = 0.f;
      if (k < INP) v = Wih0[n * INP + k];
      else if (k >= HID) v = Whh[(size_t)n * HID + (k - HID)];
      dst[i] = (_Float16)v;
    }
  } else {
    const float* src = (k0 < HID)
        ? (Wih + ((size_t)(l - 1) * HID + n) * HID + k0)
        : (Whh + ((size_t)l * HID + n) * HID + (k0 - HID));
#pragma unroll
    for (int i = 0; i < 16; ++i) dst[i] = (_Float16)src[i];
  }
  if (seg == 0) bias[r] = bih[r] + bhh[r];
}

// tanh(v) = 1 - 2/(e^{2v}+1) from raw HW ops (5 VALU, 2 trans) — r6 win.
__device__ __forceinline__ float tanh_fast(float v) {
  float e = __builtin_amdgcn_exp2f(v * 2.8853900817779268f);  // e^(2v)
  float r = __builtin_amdgcn_rcpf(e + 1.f);
  return __builtin_fmaf(-2.f, r, 1.f);
}

// Round-9: barriers -> per-wave flag sync. r8's 3165 cy/tick had ~1100 cy of
// issue and ~850 cy of chain; the rest is the 8-wave s_barrier convoy tax
// (max-of-8 jitter, 91 ticks). Slot s at step t only depends on: s-1 done t
// (IN), partner n-half done t-1 (H spans both halves), s+1 done t-2 (anti-dep
// on double buffer). Flags: vf[2+wid] = last completed local t (release:
// threadfence_block + volatile store); poll with acquire (fence after).
// Dependency potential phi = 2t+s strictly decreases -> acyclic, no deadlock.
// Flag array padded: [0,1]=pads, [2..9]=waves, [10..15]=pads, all pads = BIG,
// so s0 (no producer), s3 (no consumer), and g2's idle slots need no cases.
// No zeroing: t==0 skips H-MFMAs (h_-1 = 0 exactly). s0's IN comes from regs:
// g0 = direct per-lane x loads (exact B-frag layout), g1/g2 = SEQ reads
// (race-free vs s3's overwrite: transitively gated through the flag chain).
__global__ __launch_bounds__(512, 2) void rnn_fused(
    const float* __restrict__ x,
    const _Float16* __restrict__ Wcat,
    const float* __restrict__ bias,
    const float* __restrict__ fcW,
    const float* __restrict__ fcb,
    float* __restrict__ out) {
  extern __shared__ __align__(16) _Float16 lds[];
  volatile int* vf = (volatile int*)(lds + FLAGS_HOFF);

  const int tid    = threadIdx.x;
  const int lane15 = tid & 15;        // batch row m (MFMA D col)
  const int quad   = (tid >> 4) & 3;  // MFMA quad -> n offset quad*4+r
  const int wid    = tid >> 6;
  const int s      = wid >> 1;        // layer slot 0..3
  const int n0     = (wid & 1) * 64;  // n-half
  const int b0     = blockIdx.x * BB;

  const int rdoff  = lane15 * STRD + quad * 8;       // act-frag read base
  const int wroff  = lane15 * STRD + n0 + quad * 4;  // D write base (+nn*16)
  const int fbase  = wid & ~1;   // producers at vf[fbase,fbase+1], consumers +4,+5
  const int fpart  = 2 + (wid ^ 1);

  half8 wf[4][8];     // weights [n-subtile][k-frag] (ks 0-3 = IN, 4-7 = H)
  f32x4 bias4[4];

  for (int g = 0; g < 3; ++g) {
    const int L = g * 4 + s;  // >= NL -> idle slot (flags preset BIG)
    __syncthreads();  // all waves done with prev group's LDS
    if (tid < 16)
      vf[tid] = (tid >= 2 && tid < 10 && (g * 4 + ((tid - 2) >> 1)) < NL) ? -1 : FBIG;
    if (L < NL) {
      const _Float16* Wl = Wcat + (size_t)L * HID * 256;
#pragma unroll
      for (int nn = 0; nn < 4; ++nn) {
#pragma unroll
        for (int ks = 0; ks < 8; ++ks)
          wf[nn][ks] = *(const half8*)(Wl + (size_t)(n0 + nn * 16 + lane15) * 256 + ks * 32 + quad * 8);
        bias4[nn] = *(const f32x4*)(bias + L * HID + n0 + nn * 16 + quad * 4);
      }
    }
    __syncthreads();  // flags visible before anyone polls

    if (L < NL) {
#pragma unroll 1
      for (int t = 0; t < SEQL; ++t) {
        const int pt = (t + s) & 1;
        // --- race-free IN sources issued BEFORE the poll (latency overlap) ---
        f32x4 xa = {0.f, 0.f, 0.f, 0.f}, xb = {0.f, 0.f, 0.f, 0.f};
        half8 sf[4];
        if (s == 0) {
          if (g == 0) {
            // per-lane x load in exact B-frag layout: k = quad*8 + i
            const float* xr = x + ((size_t)(b0 + lane15) * SEQL + t) * INP;
            xa = *(const f32x4*)(xr + quad * 8);              // k q*8..+3 (q=3: 24..27)
            if (quad < 3) xb = *(const f32x4*)(xr + quad * 8 + 4);  // k 28..31 -> 0
          } else {
            const _Float16* Sb = lds + (size_t)(6 + t) * BUFH;  // SEQ(t), prev group
#pragma unroll
            for (int k = 0; k < 4; ++k) sf[k] = *(const half8*)(Sb + rdoff + k * 32);
          }
        }
        // --- flag gate: producers >= t, partner >= t-1, consumers >= t-2 ---
        while (true) {
          int p0 = vf[fbase], p1 = vf[fbase + 1], pp = vf[fpart];
          int c0 = vf[fbase + 4], c1 = vf[fbase + 5];
          if (p0 >= t && p1 >= t && pp >= t - 1 && c0 >= t - 2 && c1 >= t - 2) break;
          __builtin_amdgcn_s_sleep(1);
        }
        __threadfence_block();  // acquire: gate all data reads below

        f32x4 acc[4];
#pragma unroll
        for (int nn = 0; nn < 4; ++nn) acc[nn] = bias4[nn];

        // IN MFMAs
        if (s == 0) {
          if (g == 0) {
            half8 ax;
#pragma unroll
            for (int i = 0; i < 4; ++i) { ax[i] = (_Float16)xa[i]; ax[4 + i] = (_Float16)xb[i]; }
#pragma unroll
            for (int nn = 0; nn < 4; ++nn)
              acc[nn] = __builtin_amdgcn_mfma_f32_16x16x32_f16(wf[nn][0], ax, acc[nn], 0, 0, 0);
          } else {
#pragma unroll
            for (int k = 0; k < 4; ++k)
#pragma unroll
              for (int nn = 0; nn < 4; ++nn)
                acc[nn] = __builtin_amdgcn_mfma_f32_16x16x32_f16(wf[nn][k], sf[k], acc[nn], 0, 0, 0);
          }
        } else {
          const _Float16* INb = lds + (size_t)((s - 1) * 2 + (1 - pt)) * BUFH;
          half8 af[4];
#pragma unroll
          for (int k = 0; k < 4; ++k) af[k] = *(const half8*)(INb + rdoff + k * 32);
#pragma unroll
          for (int k = 0; k < 4; ++k)
#pragma unroll
            for (int nn = 0; nn < 4; ++nn)
              acc[nn] = __builtin_amdgcn_mfma_f32_16x16x32_f16(wf[nn][k], af[k], acc[nn], 0, 0, 0);
        }
        // H MFMAs (h_{-1} = 0 -> skip at t==0; replaces all LDS zeroing)
        if (t > 0) {
          const _Float16* Hb = (s == 3) ? lds + (size_t)(6 + (t - 1)) * BUFH
                                        : lds + (size_t)(s * 2 + (1 - pt)) * BUFH;
          half8 ah[4];
#pragma unroll
          for (int k = 0; k < 4; ++k) ah[k] = *(const half8*)(Hb + rdoff + k * 32);
#pragma unroll
          for (int k = 0; k < 4; ++k)
#pragma unroll
            for (int nn = 0; nn < 4; ++nn)
              acc[nn] = __builtin_amdgcn_mfma_f32_16x16x32_f16(wf[nn][4 + k], ah[k], acc[nn], 0, 0, 0);
        }
        // tanh + LDS write
        _Float16* Ob = (s == 3) ? lds + (size_t)(6 + t) * BUFH
                                : lds + (size_t)(s * 2 + pt) * BUFH;
#pragma unroll
        for (int nn = 0; nn < 4; ++nn) {
          half4 o;
#pragma unroll
          for (int r = 0; r < 4; ++r) o[r] = (_Float16)tanh_fast(acc[nn][r]);
          *(half4*)(Ob + wroff + nn * 16) = o;
        }
        // release: data committed before flag bump
        __threadfence_block();
        if ((tid & 63) == 0) vf[2 + wid] = t;
      }
      __threadfence_block();
      if ((tid & 63) == 0) vf[2 + wid] = FBIG;
    }
  }
  __syncthreads();

  // --- FC on layer-9 h at t=27: g2 slot1, pt=(27+1)&1=0 -> O(1,0) = slot 2 ---
  if (tid < BB * NC) {
    int c = tid >> 4;
    int b = tid & 15;
    float acc = fcb[c];
    const float* wr = fcW + c * HID;
    const _Float16* hr = lds + 2 * BUFH + b * STRD;
#pragma unroll
    for (int k0 = 0; k0 < HID; k0 += 8) {
      half8 h = *(const half8*)(hr + k0);
      f32x4 w0 = *(const f32x4*)(wr + k0);
      f32x4 w1 = *(const f32x4*)(wr + k0 + 4);
#pragma unroll
      for (int j = 0; j < 4; ++j)
        acc += (float)h[j] * w0[j] + (float)h[j + 4] * w1[j];
    }
    out[(size_t)(b0 + b) * NC + c] = acc;
  }
}

extern "C" void kernel_launch(void* const* d_in, const int* in_sizes, int n_in,
                              void* d_out, int out_size, void* d_ws, size_t ws_size,
                              hipStream_t stream) {
  const float* x    = (const float*)d_in[0];
  const float* Wih0 = (const float*)d_in[1];
  const float* Wih  = (const float*)d_in[2];
  const float* Whh  = (const float*)d_in[3];
  const float* bih  = (const float*)d_in[4];
  const float* bhh  = (const float*)d_in[5];
  const float* fcW  = (const float*)d_in[6];
  const float* fcb  = (const float*)d_in[7];
  float* out = (float*)d_out;

  _Float16* Wcat = (_Float16*)((char*)d_ws + WS_WCAT_OFF);
  float*    bs   = (float*)((char*)d_ws + WS_BIAS_OFF);

  static bool attr_done = false;
  if (!attr_done) {
    hipFuncSetAttribute(reinterpret_cast<const void*>(rnn_fused),
                        hipFuncAttributeMaxDynamicSharedMemorySize, LDS_BYTES);
    attr_done = true;
  }

  convert_weights<<<dim3(80), dim3(256), 0, stream>>>(Wih0, Wih, Whh, bih, bhh, Wcat, bs);
  rnn_fused<<<dim3(BATCH / BB), dim3(512), LDS_BYTES, stream>>>(x, Wcat, bs, fcW, fcb, out);
}

// Round 10
// 178.276 us; speedup vs baseline: 1.0955x; 1.0955x over previous
//
#include <hip/hip_runtime.h>
#include <cstdint>
#include <cstddef>

#define HID 128
#define SEQL 28
#define INP 28
#define NL 10
#define NC 10
#define BATCH 4096
#define BB 16             // batch rows per block (1 block/CU; r7 settled occupancy)
#define STRD 136          // padded row stride in halfs (272 B, b128-aligned)
#define BUFH (16 * STRD)  // halfs per 16x128 activation buffer (4352 B)

// LDS map (dynamic): O(s,p) = slot 2s+p (s=0..2, slots 0..5); SEQ(t) = slot
// 6+t (t=0..27) -> 34 slots x 4352 B = 147968 B. s3 reads/writes SEQ directly
// (its H = own SEQ(t-1)); s0 reads SEQ (g1/g2) or global x via regs (g0).
// No X slots, no Z slot, no zeroing: t==0 skips the H-MFMA block (h_-1 = 0).
#define NSLOT 34
#define LDS_BYTES (NSLOT * BUFH * 2)

typedef _Float16 half8 __attribute__((ext_vector_type(8)));
typedef _Float16 half4 __attribute__((ext_vector_type(4)));
typedef float    f32x4 __attribute__((ext_vector_type(4)));

// ---------------- ws layout (bytes) ----------------
// Wcat : [NL][HID][256] f16 : 655360 @ 0   row n: [Wih(128, l0 zero-padded) | Whh(128)]
// bias : [NL][HID] f32      : 5120   @ 655360   (b_ih + b_hh)
#define WS_WCAT_OFF 0
#define WS_BIAS_OFF 655360

__global__ void convert_weights(const float* __restrict__ Wih0,
                                const float* __restrict__ Wih,
                                const float* __restrict__ Whh,
                                const float* __restrict__ bih,
                                const float* __restrict__ bhh,
                                _Float16* __restrict__ Wcat,
                                float* __restrict__ bias) {
  int tg = blockIdx.x * blockDim.x + threadIdx.x;
  if (tg >= NL * HID * 16) return;
  int r = tg >> 4, seg = tg & 15;
  int l = r / HID, n = r % HID;
  int k0 = seg * 16;
  _Float16* dst = Wcat + (size_t)r * 256 + k0;
  if (l == 0) {
#pragma unroll
    for (int i = 0; i < 16; ++i) {
      int k = k0 + i;
      float v = 0.f;
      if (k < INP) v = Wih0[n * INP + k];
      else if (k >= HID) v = Whh[(size_t)n * HID + (k - HID)];
      dst[i] = (_Float16)v;
    }
  } else {
    const float* src = (k0 < HID)
        ? (Wih + ((size_t)(l - 1) * HID + n) * HID + k0)
        : (Whh + ((size_t)l * HID + n) * HID + (k0 - HID));
#pragma unroll
    for (int i = 0; i < 16; ++i) dst[i] = (_Float16)src[i];
  }
  if (seg == 0) bias[r] = bih[r] + bhh[r];
}

// tanh(v) = 1 - 2/(e^{2v}+1) from raw HW ops (5 VALU, 2 trans) — r6 win.
__device__ __forceinline__ float tanh_fast(float v) {
  float e = __builtin_amdgcn_exp2f(v * 2.8853900817779268f);  // e^(2v)
  float r = __builtin_amdgcn_rcpf(e + 1.f);
  return __builtin_fmaf(-2.f, r, 1.f);
}

// Light workgroup barrier: orders LDS (lgkmcnt(0)) but does NOT drain vmcnt.
__device__ __forceinline__ void barrier_light() {
  __builtin_amdgcn_sched_barrier(0);
  asm volatile("s_waitcnt lgkmcnt(0)" ::: "memory");
  __builtin_amdgcn_s_barrier();
  __builtin_amdgcn_sched_barrier(0);
}

// Round-10 = round-8 (120 us, measured best) + r9's proven-safe pieces, sync
// untouched (r9 refuted the convoy theory: flags cost MORE than s_barrier).
//  - s0/g0 x: per-lane global loads in exact B-frag layout, depth-1 reg
//    ping-pong prefetch (issued tick-end, used next tick); f32->f16 at load
//    so the buffer is 8 regs. Deletes X slots + 128-thread staging.
//  - t==0 skips H-MFMAs (h_-1 = 0 exactly) -> all LDS zeroing deleted.
//  - one __syncthreads per group (was 2; zeroing gone).
// Tick tau, pt=tau&1: slot s computes t=tau-s.
//   INb: s==0 ? (g==0 ? reg ax : SEQ(t)) : O(s-1,1-pt)
//   Hb (t>0): s==3 ? SEQ(t-1) : O(s,1-pt);   Ob: s==3 ? SEQ(t) : O(s,pt)
// Hazards (all via the per-tick barrier, as r8): consumer of O(s,pt) reads at
// tau+1, overwrite at tau+2; s0 reads SEQ(t) at tau=t, s3 overwrites at t+3;
// cross-group SEQ ordered by the group __syncthreads.
__global__ __launch_bounds__(512, 2) void rnn_fused(
    const float* __restrict__ x,
    const _Float16* __restrict__ Wcat,
    const float* __restrict__ bias,
    const float* __restrict__ fcW,
    const float* __restrict__ fcb,
    float* __restrict__ out) {
  extern __shared__ __align__(16) _Float16 lds[];

  const int tid    = threadIdx.x;
  const int lane15 = tid & 15;        // batch row m (MFMA D col)
  const int quad   = (tid >> 4) & 3;  // MFMA quad -> n offset quad*4+r
  const int wid    = tid >> 6;
  const int s      = wid >> 1;        // layer slot 0..3
  const int n0     = (wid & 1) * 64;  // n-half
  const int b0     = blockIdx.x * BB;

  const int rdoff = lane15 * STRD + quad * 8;       // act-frag read base
  const int wroff = lane15 * STRD + n0 + quad * 4;  // D write base (+nn*16)

  half8 wf[4][8];     // weights [n-subtile][k-frag] (ks 0-3 = IN, 4-7 = H)
  f32x4 bias4[4];
  half8 axbuf[2];     // s0/g0 x frag ping-pong (indexed by literal pt)

  // per-lane x load in exact B-frag layout: k = quad*8 + i (k>=28 -> 0).
  // Row base (b*28+t)*28 floats = 112B-aligned -> 16B-aligned f32x4 loads.
  auto load_x = [&](int t, int sl) {
    const float* xr = x + ((size_t)(b0 + lane15) * SEQL + t) * INP;
    f32x4 xa = *(const f32x4*)(xr + quad * 8);
    f32x4 xb = {0.f, 0.f, 0.f, 0.f};
    if (quad < 3) xb = *(const f32x4*)(xr + quad * 8 + 4);
    half8 ax;
#pragma unroll
    for (int i = 0; i < 4; ++i) { ax[i] = (_Float16)xa[i]; ax[4 + i] = (_Float16)xb[i]; }
    axbuf[sl] = ax;
  };

  for (int g = 0; g < 3; ++g) {
    const int L = g * 4 + s;  // >= NL -> idle slot (barriers only)
    if (L < NL) {
      const _Float16* Wl = Wcat + (size_t)L * HID * 256;
#pragma unroll
      for (int nn = 0; nn < 4; ++nn) {
#pragma unroll
        for (int ks = 0; ks < 8; ++ks)
          wf[nn][ks] = *(const half8*)(Wl + (size_t)(n0 + nn * 16 + lane15) * 256 + ks * 32 + quad * 8);
        bias4[nn] = *(const f32x4*)(bias + L * HID + n0 + nn * 16 + quad * 4);
      }
    }
    // group barrier: prev group's LDS reads complete before SEQ overwrite
    __syncthreads();
    if (g == 0 && s == 0) load_x(0, 0);

    auto tick = [&](int tau, int pt) {
      barrier_light();
      const int t = tau - s;
      if (L < NL && (unsigned)t < SEQL) {
        _Float16* Ob = (s == 3) ? lds + (size_t)(6 + t) * BUFH
                                : lds + (size_t)(2 * s + pt) * BUFH;
        auto tw = [&](int nn, f32x4 av) {
          half4 o;
#pragma unroll
          for (int r = 0; r < 4; ++r) o[r] = (_Float16)tanh_fast(av[r]);
          *(half4*)(Ob + wroff + nn * 16) = o;
        };

        if (g == 0 && s == 0) {
          // layer 0: x-input 32 k-wide, from registers (no LDS staging)
          half8 ax = axbuf[pt];
          if (t > 0) {
            const _Float16* Hb = lds + (size_t)(1 - pt) * BUFH;  // O(0,1-pt)
            half8 ah[4];
#pragma unroll
            for (int ks = 0; ks < 4; ++ks) ah[ks] = *(const half8*)(Hb + rdoff + ks * 32);
            f32x4 a0 = bias4[0], a1 = bias4[1];
            a0 = __builtin_amdgcn_mfma_f32_16x16x32_f16(wf[0][0], ax, a0, 0, 0, 0);
            a1 = __builtin_amdgcn_mfma_f32_16x16x32_f16(wf[1][0], ax, a1, 0, 0, 0);
#pragma unroll
            for (int ks = 0; ks < 4; ++ks) {
              a0 = __builtin_amdgcn_mfma_f32_16x16x32_f16(wf[0][4 + ks], ah[ks], a0, 0, 0, 0);
              a1 = __builtin_amdgcn_mfma_f32_16x16x32_f16(wf[1][4 + ks], ah[ks], a1, 0, 0, 0);
            }
            f32x4 a2 = bias4[2], a3 = bias4[3];
            a2 = __builtin_amdgcn_mfma_f32_16x16x32_f16(wf[2][0], ax, a2, 0, 0, 0);
            a3 = __builtin_amdgcn_mfma_f32_16x16x32_f16(wf[3][0], ax, a3, 0, 0, 0);
#pragma unroll
            for (int ks = 0; ks < 4; ++ks) {
              a2 = __builtin_amdgcn_mfma_f32_16x16x32_f16(wf[2][4 + ks], ah[ks], a2, 0, 0, 0);
              a3 = __builtin_amdgcn_mfma_f32_16x16x32_f16(wf[3][4 + ks], ah[ks], a3, 0, 0, 0);
            }
            tw(0, a0); tw(1, a1); tw(2, a2); tw(3, a3);
          } else {
            f32x4 a0 = bias4[0], a1 = bias4[1], a2 = bias4[2], a3 = bias4[3];
            a0 = __builtin_amdgcn_mfma_f32_16x16x32_f16(wf[0][0], ax, a0, 0, 0, 0);
            a1 = __builtin_amdgcn_mfma_f32_16x16x32_f16(wf[1][0], ax, a1, 0, 0, 0);
            a2 = __builtin_amdgcn_mfma_f32_16x16x32_f16(wf[2][0], ax, a2, 0, 0, 0);
            a3 = __builtin_amdgcn_mfma_f32_16x16x32_f16(wf[3][0], ax, a3, 0, 0, 0);
            tw(0, a0); tw(1, a1); tw(2, a2); tw(3, a3);
          }
        } else {
          const _Float16* INb = (s == 0) ? lds + (size_t)(6 + t) * BUFH
                                         : lds + (size_t)(2 * (s - 1) + (1 - pt)) * BUFH;
          half8 af[8];
#pragma unroll
          for (int ks = 0; ks < 4; ++ks) af[ks] = *(const half8*)(INb + rdoff + ks * 32);
          if (t > 0) {
            const _Float16* Hb = (s == 3) ? lds + (size_t)(6 + (t - 1)) * BUFH
                                          : lds + (size_t)(2 * s + (1 - pt)) * BUFH;
#pragma unroll
            for (int ks = 0; ks < 4; ++ks) af[4 + ks] = *(const half8*)(Hb + rdoff + ks * 32);
            f32x4 a0 = bias4[0], a1 = bias4[1];
#pragma unroll
            for (int i = 0; i < 8; ++i) {
              a0 = __builtin_amdgcn_mfma_f32_16x16x32_f16(wf[0][i], af[i], a0, 0, 0, 0);
              a1 = __builtin_amdgcn_mfma_f32_16x16x32_f16(wf[1][i], af[i], a1, 0, 0, 0);
            }
            f32x4 a2 = bias4[2], a3 = bias4[3];
#pragma unroll
            for (int i = 0; i < 8; ++i) {
              a2 = __builtin_amdgcn_mfma_f32_16x16x32_f16(wf[2][i], af[i], a2, 0, 0, 0);
              a3 = __builtin_amdgcn_mfma_f32_16x16x32_f16(wf[3][i], af[i], a3, 0, 0, 0);
            }
            tw(0, a0); tw(1, a1); tw(2, a2); tw(3, a3);
          } else {
            f32x4 a0 = bias4[0], a1 = bias4[1];
#pragma unroll
            for (int i = 0; i < 4; ++i) {
              a0 = __builtin_amdgcn_mfma_f32_16x16x32_f16(wf[0][i], af[i], a0, 0, 0, 0);
              a1 = __builtin_amdgcn_mfma_f32_16x16x32_f16(wf[1][i], af[i], a1, 0, 0, 0);
            }
            f32x4 a2 = bias4[2], a3 = bias4[3];
#pragma unroll
            for (int i = 0; i < 4; ++i) {
              a2 = __builtin_amdgcn_mfma_f32_16x16x32_f16(wf[2][i], af[i], a2, 0, 0, 0);
              a3 = __builtin_amdgcn_mfma_f32_16x16x32_f16(wf[3][i], af[i], a3, 0, 0, 0);
            }
            tw(0, a0); tw(1, a1); tw(2, a2); tw(3, a3);
          }
        }
      }
      // issue next x load at tick end (consumed next tick -> latency covered)
      if (g == 0 && s == 0 && tau + 1 < SEQL) load_x(tau + 1, 1 - pt);
    };

    const int Tend = (g == 2) ? 28 : 30;  // even; ticks 0..Tend
    for (int tau = 0; tau < Tend; tau += 2) {
      tick(tau, 0);
      tick(tau + 1, 1);
    }
    tick(Tend, 0);
  }
  __syncthreads();

  // --- FC on layer-9 h at t=27: g2 slot1, tau=28 pt=0 -> O(1,0) = slot 2 ---
  if (tid < BB * NC) {
    int c = tid >> 4;
    int b = tid & 15;
    float acc = fcb[c];
    const float* wr = fcW + c * HID;
    const _Float16* hr = lds + 2 * BUFH + b * STRD;
#pragma unroll
    for (int k0 = 0; k0 < HID; k0 += 8) {
      half8 h = *(const half8*)(hr + k0);
      f32x4 w0 = *(const f32x4*)(wr + k0);
      f32x4 w1 = *(const f32x4*)(wr + k0 + 4);
#pragma unroll
      for (int j = 0; j < 4; ++j)
        acc += (float)h[j] * w0[j] + (float)h[j + 4] * w1[j];
    }
    out[(size_t)(b0 + b) * NC + c] = acc;
  }
}

extern "C" void kernel_launch(void* const* d_in, const int* in_sizes, int n_in,
                              void* d_out, int out_size, void* d_ws, size_t ws_size,
                              hipStream_t stream) {
  const float* x    = (const float*)d_in[0];
  const float* Wih0 = (const float*)d_in[1];
  const float* Wih  = (const float*)d_in[2];
  const float* Whh  = (const float*)d_in[3];
  const float* bih  = (const float*)d_in[4];
  const float* bhh  = (const float*)d_in[5];
  const float* fcW  = (const float*)d_in[6];
  const float* fcb  = (const float*)d_in[7];
  float* out = (float*)d_out;

  _Float16* Wcat = (_Float16*)((char*)d_ws + WS_WCAT_OFF);
  float*    bs   = (float*)((char*)d_ws + WS_BIAS_OFF);

  static bool attr_done = false;
  if (!attr_done) {
    hipFuncSetAttribute(reinterpret_cast<const void*>(rnn_fused),
                        hipFuncAttributeMaxDynamicSharedMemorySize, LDS_BYTES);
    attr_done = true;
  }

  convert_weights<<<dim3(80), dim3(256), 0, stream>>>(Wih0, Wih, Whh, bih, bhh, Wcat, bs);
  rnn_fused<<<dim3(BATCH / BB), dim3(512), LDS_BYTES, stream>>>(x, Wcat, bs, fcW, fcb, out);
}

// Round 11
// 176.562 us; speedup vs baseline: 1.1062x; 1.0097x over previous
//
#include <hip/hip_runtime.h>
#include <cstdint>
#include <cstddef>

#define HID 128
#define SEQL 28
#define INP 28
#define NL 10
#define NC 10
#define BATCH 4096
#define BB 16             // batch rows per block (1 block/CU; r7 settled occupancy)
#define STRD 136          // padded row stride in halfs (272 B, b128-aligned)
#define BUFH (16 * STRD)  // halfs per 16x128 activation buffer (4352 B)

// LDS map (dynamic): O(s,p) = slot 2s+p (s=0..2, slots 0..5); SEQ(t) = slot
// 6+t (t=0..27) -> 34 slots x 4352 B = 147968 B. s3 reads/writes SEQ directly
// (its H = own SEQ(t-1)); s0 reads SEQ (g1/g2) or global x via regs (g0).
// No X slots, no Z slot, no zeroing: t==0 skips the H-MFMA block (h_-1 = 0).
#define NSLOT 34
#define LDS_BYTES (NSLOT * BUFH * 2)

typedef _Float16 half8 __attribute__((ext_vector_type(8)));
typedef _Float16 half4 __attribute__((ext_vector_type(4)));
typedef float    f32x4 __attribute__((ext_vector_type(4)));

// ---------------- ws layout (bytes) ----------------
// Wcat : [NL][HID][256] f16 : 655360 @ 0   row n: [Wih(128, l0 zero-padded) | Whh(128)]
// bias : [NL][HID] f32      : 5120   @ 655360   (b_ih + b_hh)
#define WS_WCAT_OFF 0
#define WS_BIAS_OFF 655360

__global__ void convert_weights(const float* __restrict__ Wih0,
                                const float* __restrict__ Wih,
                                const float* __restrict__ Whh,
                                const float* __restrict__ bih,
                                const float* __restrict__ bhh,
                                _Float16* __restrict__ Wcat,
                                float* __restrict__ bias) {
  int tg = blockIdx.x * blockDim.x + threadIdx.x;
  if (tg >= NL * HID * 16) return;
  int r = tg >> 4, seg = tg & 15;
  int l = r / HID, n = r % HID;
  int k0 = seg * 16;
  _Float16* dst = Wcat + (size_t)r * 256 + k0;
  if (l == 0) {
#pragma unroll
    for (int i = 0; i < 16; ++i) {
      int k = k0 + i;
      float v = 0.f;
      if (k < INP) v = Wih0[n * INP + k];
      else if (k >= HID) v = Whh[(size_t)n * HID + (k - HID)];
      dst[i] = (_Float16)v;
    }
  } else {
    const float* src = (k0 < HID)
        ? (Wih + ((size_t)(l - 1) * HID + n) * HID + k0)
        : (Whh + ((size_t)l * HID + n) * HID + (k0 - HID));
#pragma unroll
    for (int i = 0; i < 16; ++i) dst[i] = (_Float16)src[i];
  }
  if (seg == 0) bias[r] = bih[r] + bhh[r];
}

// tanh(v) = 1 - 2/(e^{2v}+1) from raw HW ops (5 VALU, 2 trans) — r6 win.
__device__ __forceinline__ float tanh_fast(float v) {
  float e = __builtin_amdgcn_exp2f(v * 2.8853900817779268f);  // e^(2v)
  float r = __builtin_amdgcn_rcpf(e + 1.f);
  return __builtin_fmaf(-2.f, r, 1.f);
}

// Light workgroup barrier: orders LDS (lgkmcnt(0)) but does NOT drain vmcnt.
__device__ __forceinline__ void barrier_light() {
  __builtin_amdgcn_sched_barrier(0);
  asm volatile("s_waitcnt lgkmcnt(0)" ::: "memory");
  __builtin_amdgcn_s_barrier();
  __builtin_amdgcn_sched_barrier(0);
}

// Round-11 = round-10 (116 us) with ONE change: the 32 MFMAs per cell run as
// a 4-WIDE round-robin (a0,a1,a2,a3 per k-frag) instead of two sequential
// 2-wide pair blocks. Doubles dependent-latency hiding width (4x4.85 ~ 19 cy
// issue per dep step vs ~10) and consumes each af[i] right after its ds_read
// returns (read latency pipelined into the chain; previously pair-B re-walked
// all 8 frags after pair-A finished). Registers unchanged (16 acc f32 — the
// 252-combined-regs/wave wall of r5/r7 leaves only ~8 spare).
// Tick tau, pt=tau&1: slot s computes t=tau-s.
//   INb: s==0 ? (g==0 ? reg ax : SEQ(t)) : O(s-1,1-pt)
//   Hb (t>0): s==3 ? SEQ(t-1) : O(s,1-pt);   Ob: s==3 ? SEQ(t) : O(s,pt)
// Hazards (via per-tick barrier): consumer of O(s,pt) reads at tau+1,
// overwrite at tau+2; s0 reads SEQ(t) at tau=t, s3 overwrites at t+3;
// cross-group SEQ ordered by the group __syncthreads.
__global__ __launch_bounds__(512, 2) void rnn_fused(
    const float* __restrict__ x,
    const _Float16* __restrict__ Wcat,
    const float* __restrict__ bias,
    const float* __restrict__ fcW,
    const float* __restrict__ fcb,
    float* __restrict__ out) {
  extern __shared__ __align__(16) _Float16 lds[];

  const int tid    = threadIdx.x;
  const int lane15 = tid & 15;        // batch row m (MFMA D col)
  const int quad   = (tid >> 4) & 3;  // MFMA quad -> n offset quad*4+r
  const int wid    = tid >> 6;
  const int s      = wid >> 1;        // layer slot 0..3
  const int n0     = (wid & 1) * 64;  // n-half
  const int b0     = blockIdx.x * BB;

  const int rdoff = lane15 * STRD + quad * 8;       // act-frag read base
  const int wroff = lane15 * STRD + n0 + quad * 4;  // D write base (+nn*16)

  half8 wf[4][8];     // weights [n-subtile][k-frag] (ks 0-3 = IN, 4-7 = H)
  f32x4 bias4[4];
  half8 axbuf[2];     // s0/g0 x frag ping-pong (indexed by literal pt)

  // per-lane x load in exact B-frag layout: k = quad*8 + i (k>=28 -> 0).
  auto load_x = [&](int t, int sl) {
    const float* xr = x + ((size_t)(b0 + lane15) * SEQL + t) * INP;
    f32x4 xa = *(const f32x4*)(xr + quad * 8);
    f32x4 xb = {0.f, 0.f, 0.f, 0.f};
    if (quad < 3) xb = *(const f32x4*)(xr + quad * 8 + 4);
    half8 ax;
#pragma unroll
    for (int i = 0; i < 4; ++i) { ax[i] = (_Float16)xa[i]; ax[4 + i] = (_Float16)xb[i]; }
    axbuf[sl] = ax;
  };

  for (int g = 0; g < 3; ++g) {
    const int L = g * 4 + s;  // >= NL -> idle slot (barriers only)
    if (L < NL) {
      const _Float16* Wl = Wcat + (size_t)L * HID * 256;
#pragma unroll
      for (int nn = 0; nn < 4; ++nn) {
#pragma unroll
        for (int ks = 0; ks < 8; ++ks)
          wf[nn][ks] = *(const half8*)(Wl + (size_t)(n0 + nn * 16 + lane15) * 256 + ks * 32 + quad * 8);
        bias4[nn] = *(const f32x4*)(bias + L * HID + n0 + nn * 16 + quad * 4);
      }
    }
    // group barrier: prev group's LDS reads complete before SEQ overwrite
    __syncthreads();
    if (g == 0 && s == 0) load_x(0, 0);

    auto tick = [&](int tau, int pt) {
      barrier_light();
      const int t = tau - s;
      if (L < NL && (unsigned)t < SEQL) {
        _Float16* Ob = (s == 3) ? lds + (size_t)(6 + t) * BUFH
                                : lds + (size_t)(2 * s + pt) * BUFH;
        auto tw = [&](int nn, f32x4 av) {
          half4 o;
#pragma unroll
          for (int r = 0; r < 4; ++r) o[r] = (_Float16)tanh_fast(av[r]);
          *(half4*)(Ob + wroff + nn * 16) = o;
        };
        f32x4 a0 = bias4[0], a1 = bias4[1], a2 = bias4[2], a3 = bias4[3];

        if (g == 0 && s == 0) {
          // layer 0: x-input 32 k-wide, from registers (no LDS staging)
          half8 ax = axbuf[pt];
          a0 = __builtin_amdgcn_mfma_f32_16x16x32_f16(wf[0][0], ax, a0, 0, 0, 0);
          a1 = __builtin_amdgcn_mfma_f32_16x16x32_f16(wf[1][0], ax, a1, 0, 0, 0);
          a2 = __builtin_amdgcn_mfma_f32_16x16x32_f16(wf[2][0], ax, a2, 0, 0, 0);
          a3 = __builtin_amdgcn_mfma_f32_16x16x32_f16(wf[3][0], ax, a3, 0, 0, 0);
          if (t > 0) {
            const _Float16* Hb = lds + (size_t)(1 - pt) * BUFH;  // O(0,1-pt)
            half8 ah[4];
#pragma unroll
            for (int ks = 0; ks < 4; ++ks) ah[ks] = *(const half8*)(Hb + rdoff + ks * 32);
#pragma unroll
            for (int ks = 0; ks < 4; ++ks) {  // 4-wide round-robin
              a0 = __builtin_amdgcn_mfma_f32_16x16x32_f16(wf[0][4 + ks], ah[ks], a0, 0, 0, 0);
              a1 = __builtin_amdgcn_mfma_f32_16x16x32_f16(wf[1][4 + ks], ah[ks], a1, 0, 0, 0);
              a2 = __builtin_amdgcn_mfma_f32_16x16x32_f16(wf[2][4 + ks], ah[ks], a2, 0, 0, 0);
              a3 = __builtin_amdgcn_mfma_f32_16x16x32_f16(wf[3][4 + ks], ah[ks], a3, 0, 0, 0);
            }
          }
          tw(0, a0); tw(1, a1); tw(2, a2); tw(3, a3);
        } else {
          const _Float16* INb = (s == 0) ? lds + (size_t)(6 + t) * BUFH
                                         : lds + (size_t)(2 * (s - 1) + (1 - pt)) * BUFH;
          half8 af[8];
#pragma unroll
          for (int ks = 0; ks < 4; ++ks) af[ks] = *(const half8*)(INb + rdoff + ks * 32);
          if (t > 0) {
            const _Float16* Hb = (s == 3) ? lds + (size_t)(6 + (t - 1)) * BUFH
                                          : lds + (size_t)(2 * s + (1 - pt)) * BUFH;
#pragma unroll
            for (int ks = 0; ks < 4; ++ks) af[4 + ks] = *(const half8*)(Hb + rdoff + ks * 32);
#pragma unroll
            for (int i = 0; i < 8; ++i) {  // 4-wide round-robin, frag-major:
              // consumes af[i] as soon as its ds_read returns; 4 independent
              // dep-chains in flight -> ~19 cy issue per dep step.
              a0 = __builtin_amdgcn_mfma_f32_16x16x32_f16(wf[0][i], af[i], a0, 0, 0, 0);
              a1 = __builtin_amdgcn_mfma_f32_16x16x32_f16(wf[1][i], af[i], a1, 0, 0, 0);
              a2 = __builtin_amdgcn_mfma_f32_16x16x32_f16(wf[2][i], af[i], a2, 0, 0, 0);
              a3 = __builtin_amdgcn_mfma_f32_16x16x32_f16(wf[3][i], af[i], a3, 0, 0, 0);
            }
          } else {
#pragma unroll
            for (int i = 0; i < 4; ++i) {
              a0 = __builtin_amdgcn_mfma_f32_16x16x32_f16(wf[0][i], af[i], a0, 0, 0, 0);
              a1 = __builtin_amdgcn_mfma_f32_16x16x32_f16(wf[1][i], af[i], a1, 0, 0, 0);
              a2 = __builtin_amdgcn_mfma_f32_16x16x32_f16(wf[2][i], af[i], a2, 0, 0, 0);
              a3 = __builtin_amdgcn_mfma_f32_16x16x32_f16(wf[3][i], af[i], a3, 0, 0, 0);
            }
          }
          tw(0, a0); tw(1, a1); tw(2, a2); tw(3, a3);
        }
      }
      // issue next x load at tick end (consumed next tick -> latency covered)
      if (g == 0 && s == 0 && tau + 1 < SEQL) load_x(tau + 1, 1 - pt);
    };

    const int Tend = (g == 2) ? 28 : 30;  // even; ticks 0..Tend
    for (int tau = 0; tau < Tend; tau += 2) {
      tick(tau, 0);
      tick(tau + 1, 1);
    }
    tick(Tend, 0);
  }
  __syncthreads();

  // --- FC on layer-9 h at t=27: g2 slot1, tau=28 pt=0 -> O(1,0) = slot 2 ---
  if (tid < BB * NC) {
    int c = tid >> 4;
    int b = tid & 15;
    float acc = fcb[c];
    const float* wr = fcW + c * HID;
    const _Float16* hr = lds + 2 * BUFH + b * STRD;
#pragma unroll
    for (int k0 = 0; k0 < HID; k0 += 8) {
      half8 h = *(const half8*)(hr + k0);
      f32x4 w0 = *(const f32x4*)(wr + k0);
      f32x4 w1 = *(const f32x4*)(wr + k0 + 4);
#pragma unroll
      for (int j = 0; j < 4; ++j)
        acc += (float)h[j] * w0[j] + (float)h[j + 4] * w1[j];
    }
    out[(size_t)(b0 + b) * NC + c] = acc;
  }
}

extern "C" void kernel_launch(void* const* d_in, const int* in_sizes, int n_in,
                              void* d_out, int out_size, void* d_ws, size_t ws_size,
                              hipStream_t stream) {
  const float* x    = (const float*)d_in[0];
  const float* Wih0 = (const float*)d_in[1];
  const float* Wih  = (const float*)d_in[2];
  const float* Whh  = (const float*)d_in[3];
  const float* bih  = (const float*)d_in[4];
  const float* bhh  = (const float*)d_in[5];
  const float* fcW  = (const float*)d_in[6];
  const float* fcb  = (const float*)d_in[7];
  float* out = (float*)d_out;

  _Float16* Wcat = (_Float16*)((char*)d_ws + WS_WCAT_OFF);
  float*    bs   = (float*)((char*)d_ws + WS_BIAS_OFF);

  static bool attr_done = false;
  if (!attr_done) {
    hipFuncSetAttribute(reinterpret_cast<const void*>(rnn_fused),
                        hipFuncAttributeMaxDynamicSharedMemorySize, LDS_BYTES);
    attr_done = true;
  }

  convert_weights<<<dim3(80), dim3(256), 0, stream>>>(Wih0, Wih, Whh, bih, bhh, Wcat, bs);
  rnn_fused<<<dim3(BATCH / BB), dim3(512), LDS_BYTES, stream>>>(x, Wcat, bs, fcW, fcb, out);
}